// Round 2
// baseline (232.985 us; speedup 1.0000x reference)
//
#include <hip/hip_runtime.h>

// EMA y_t = 0.1*x_t + 0.9*y_{t-1} along T of x[B=64][T=8192][F=64], fp32.
// R6: defeat the compiler's load serialization. R5 rocprof: VGPR=28 (!) ->
// the PF=32 prefetch batch was fused into the serial FMA chain (1 load in
// flight, full HBM latency per load: 192 loads x ~900cy = 72us ~ measured
// 80us, hbm 2.9 TB/s, VALUBusy 4.5%). Fix:
//  - sched_barrier(0) after every 32-load batch: loads can't sink, FMAs
//    can't hoist -> whole batch issues back-to-back and stays live.
//  - depth-2 software pipeline, fully unrolled with STATIC A/B buffers
//    (rule #20: no runtime-indexed buffers): issue batch k+1 before
//    consuming batch k -> one full batch latency hidden per step,
//    16KB/wave in flight, 16 waves/CU -> HBM-bound.
//  - __launch_bounds__(256,4): 128-VGPR budget so the allocator doesn't
//    re-collapse the buffers (expect ~80 VGPRs).
// Mapping unchanged from R5: 1 float/lane, wave = one (b,chunk) stream,
// L=128 stores, H=64 windup (0.9^64 ~ 1.2e-3, absmax passed at 3.9e-3),
// grid 64b x 16 = 1024 blocks x 4 waves = 16 waves/CU.

constexpr int Tn = 8192;
constexpr int Fn = 64;    // features = lanes per wave
constexpr int Ln = 128;   // chunk length (stores) = 4 batches
constexpr int Hn = 64;    // windup history = 2 batches
constexpr int PF = 32;    // batch size (loads in flight per buffer)
constexpr float ALPHA = 0.1f;
constexpr float OMA   = 0.9f;

__global__ __launch_bounds__(256, 4) void ema_kernel(const float* __restrict__ x,
                                                     float* __restrict__ y) {
    const int f  = threadIdx.x & 63;           // feature = lane
    const int w  = threadIdx.x >> 6;           // wave in block: 0..3
    const int b  = blockIdx.x >> 4;            // 0..63
    const int c  = ((blockIdx.x & 15) << 2) | w;   // chunk 0..63

    const size_t base = (size_t)b * (Tn * Fn) + f;
    const float* __restrict__ xp = x + base;
    float*       __restrict__ yp = y + base;

    const int t0 = c * Ln;

    float A[PF], B[PF];
    float s;

    // Issue a full 32-load batch; fence so no FMA hoists above and no load
    // sinks below -> batch stays intact in the emitted code.
    auto LOAD = [&](float (&buf)[PF], int t) {
        #pragma unroll
        for (int i = 0; i < PF; ++i) buf[i] = xp[(size_t)(t + i) * Fn];
        __builtin_amdgcn_sched_barrier(0);
    };
    // Windup: consume batch, no stores.
    auto ACC = [&](float (&buf)[PF]) {
        #pragma unroll
        for (int i = 0; i < PF; ++i) s = fmaf(OMA, s, ALPHA * buf[i]);
    };
    // Main: consume batch with nontemporal stores.
    auto ACCST = [&](float (&buf)[PF], int t) {
        #pragma unroll
        for (int i = 0; i < PF; ++i) {
            s = fmaf(OMA, s, ALPHA * buf[i]);
            __builtin_nontemporal_store(s, &yp[(size_t)(t + i) * Fn]);
        }
    };

    if (c != 0) {
        // 6 batches: 2 windup + 4 stored, depth-2 pipelined.
        s = 0.0f;
        LOAD(A, t0 - 64);
        LOAD(B, t0 - 32);
        ACC(A);            LOAD(A, t0);
        ACC(B);            LOAD(B, t0 + 32);
        ACCST(A, t0);      LOAD(A, t0 + 64);
        ACCST(B, t0 + 32); LOAD(B, t0 + 96);
        ACCST(A, t0 + 64);
        ACCST(B, t0 + 96);
    } else {
        // chunk 0 exact: 4 stored batches, first peeled (y_0 = x_0).
        LOAD(A, 0);
        LOAD(B, 32);
        s = A[0];
        __builtin_nontemporal_store(s, &yp[0]);
        #pragma unroll
        for (int i = 1; i < PF; ++i) {
            s = fmaf(OMA, s, ALPHA * A[i]);
            __builtin_nontemporal_store(s, &yp[(size_t)i * Fn]);
        }
        LOAD(A, 64);
        ACCST(B, 32);      LOAD(B, 96);
        ACCST(A, 64);
        ACCST(B, 96);
    }
}

extern "C" void kernel_launch(void* const* d_in, const int* in_sizes, int n_in,
                              void* d_out, int out_size, void* d_ws, size_t ws_size,
                              hipStream_t stream) {
    const float* x = (const float*)d_in[0];
    float*       y = (float*)d_out;
    // 64 b * 64 chunks = 4096 wave-streams; 4 waves (256 thr) per block.
    ema_kernel<<<dim3(1024), dim3(256), 0, stream>>>(x, y);
}